// Round 2
// baseline (307.644 us; speedup 1.0000x reference)
//
#include <hip/hip_runtime.h>
#include <hip/hip_bf16.h>

// ---------- types ----------
typedef __bf16 bf16x8 __attribute__((ext_vector_type(8)));
typedef float  f32x4  __attribute__((ext_vector_type(4)));

#define GLOAD_LDS16(gptr, lptr)                                                  \
  __builtin_amdgcn_global_load_lds(                                              \
      (const __attribute__((address_space(1))) void*)(gptr),                     \
      (__attribute__((address_space(3))) void*)(lptr), 16, 0, 0)

__device__ __forceinline__ unsigned short f2bf(float f) {
  __hip_bfloat16 h = __float2bfloat16(f);
  return __builtin_bit_cast(unsigned short, h);
}

// ---------- fake-quant: lane owns 4 CONSECUTIVE floats; the 128-elem block is
// the 32-lane half-wave. amax via 5-step butterfly (exact - fmax associative).
__device__ __forceinline__ void fq4(float* __restrict__ v) {
  float am = fmaxf(fmaxf(fabsf(v[0]), fabsf(v[1])),
                   fmaxf(fabsf(v[2]), fabsf(v[3])));
  am = fmaxf(am, __shfl_xor(am, 1));
  am = fmaxf(am, __shfl_xor(am, 2));
  am = fmaxf(am, __shfl_xor(am, 4));
  am = fmaxf(am, __shfl_xor(am, 8));
  am = fmaxf(am, __shfl_xor(am, 16));   // stays within each 32-lane half
  am = fmaxf(am, 1e-12f);
  const float scale = 448.0f / am;
  const float inv   = am * (1.0f / 448.0f);
  float c0 = fminf(fmaxf(v[0] * scale, -448.0f), 448.0f);
  float c1 = fminf(fmaxf(v[1] * scale, -448.0f), 448.0f);
  float c2 = fminf(fmaxf(v[2] * scale, -448.0f), 448.0f);
  float c3 = fminf(fmaxf(v[3] * scale, -448.0f), 448.0f);
  int pk = __builtin_amdgcn_cvt_pk_fp8_f32(c0, c1, 0, false);
  pk = __builtin_amdgcn_cvt_pk_fp8_f32(c2, c3, pk, true);
  v[0] = __builtin_amdgcn_cvt_f32_fp8(pk, 0) * inv;
  v[1] = __builtin_amdgcn_cvt_f32_fp8(pk, 1) * inv;
  v[2] = __builtin_amdgcn_cvt_f32_fp8(pk, 2) * inv;
  v[3] = __builtin_amdgcn_cvt_f32_fp8(pk, 3) * inv;
}

__global__ __launch_bounds__(256) void quant_x_k(const float* __restrict__ x,
                                                 unsigned short* __restrict__ xq) {
  const size_t u = (size_t)blockIdx.x * 256 + threadIdx.x;
  float v[4];
  *(float4*)v = ((const float4*)x)[u];
  fq4(v);
  union { uint2 q; unsigned short s[4]; } pk;
#pragma unroll
  for (int e = 0; e < 4; ++e) pk.s[e] = f2bf(v[e]);
  ((uint2*)xq)[u] = pk.q;
}

__global__ __launch_bounds__(256) void quant_w_k(const float* __restrict__ w,
                                                 unsigned short* __restrict__ wq) {
  const size_t u = (size_t)blockIdx.x * 256 + threadIdx.x;
  float a[4], h[4], r[4];
  *(float4*)a = ((const float4*)w)[u];
#pragma unroll
  for (int i = 0; i < 4; ++i) h[i] = a[i];
  fq4(h);
#pragma unroll
  for (int i = 0; i < 4; ++i) r[i] = a[i] - h[i];
  fq4(r);
  union { uint2 q; unsigned short s[4]; } pk;
#pragma unroll
  for (int e = 0; e < 4; ++e) pk.s[e] = f2bf(h[e] + r[e]);
  ((uint2*)wq)[u] = pk.q;
}

// ---------- GEMM: 256x256 tile, BK=64, 8 waves (2Mx4N), 8-phase pipeline ----
// Per K-tile, 4 phases: (miQ0,nj01)(miQ0,nj23)(miQ1,nj01)(miQ1,nj23), 16 MFMA
// each. Staging units = exactly the rows each phase consumes:
//   A-U01 = rows [0,64)+[128,192)   (miQ0, both wr)   A-U23 = +64
//   B-V0  = rows wc*64+[0,32) all wc (nj01)           B-V1  = +32
// Phase p stages one unit of the tile consumed 3-4 phases later; vmcnt(4) at
// six of eight phase-ends drains exactly the loads issued 3 phases earlier
// (never 0 in the main loop). Buffers strictly alternate; every stage target
// has been dead >= 1 full phase for ALL waves (checked at P3/P4, P7/P0
// boundaries). 16B chunks XOR-swizzled within each row (proven 0-conflict).
#define BM 256
#define BN 256
#define BK 64

#define VM4()  asm volatile("s_waitcnt vmcnt(4)" ::: "memory")
#define VM2()  asm volatile("s_waitcnt vmcnt(2)" ::: "memory")
#define VM0()  asm volatile("s_waitcnt vmcnt(0)" ::: "memory")
#define LG0()  do { asm volatile("s_waitcnt lgkmcnt(0)" ::: "memory");           \
                    __builtin_amdgcn_sched_barrier(0); } while (0)
#define BAR()  __builtin_amdgcn_s_barrier()

__global__ __launch_bounds__(512, 2) void gemm_bt_bias(
    const unsigned short* __restrict__ A,   // bf16 bits [M,K]
    const unsigned short* __restrict__ B,   // bf16 bits [N,K]
    const float* __restrict__ bias,         // [N]
    float* __restrict__ C,                  // [M,N]
    int M, int N, int K) {
  __shared__ unsigned short lds[65536];     // 128 KiB: A 2x16K elems, B 2x16K
  unsigned short* ldsA = lds;               // [buf][256][64]
  unsigned short* ldsB = lds + 32768;

  const int tid  = threadIdx.x;
  const int wv   = tid >> 6;
  const int lane = tid & 63;
  const int nbn  = N / BN;
  const int nbm  = M / BM;

  int bm, bn;
  if ((nbm & 7) == 0) {
    const int xcd = blockIdx.x & 7;
    const int j   = blockIdx.x >> 3;
    bn = j % nbn;
    bm = xcd * (nbm >> 3) + j / nbn;
  } else {
    bn = blockIdx.x % nbn;
    bm = blockIdx.x / nbn;
  }

  const int wr = wv >> 2;    // 0..1 (M dir, 128 rows each)
  const int wc = wv & 3;     // 0..3 (N dir, 64 cols each)

  f32x4  acc[8][4] = {};
  bf16x8 a[4][2], b01[2][2], b23[2][2];

  // ---- staging addresses (swizzle: LDS chunk c holds global chunk c^(row&7))
  const int    srcChunk = ((lane & 7) ^ ((lane >> 3) & 7)) * 8;
  const size_t laneSrc  = (size_t)(lane >> 3) * K + srcChunk;
  const unsigned short* gA = A + (size_t)bm * BM * K + laneSrc;
  const unsigned short* gB = B + (size_t)bn * BN * K + laneSrc;
  const int lr0 = wv * 16, lr1 = wv * 16 + 8;   // logical 8-row groups
  auto arow = [](int mq, int lr) { return mq * 64 + (lr < 64 ? lr : 64 + lr); };
  auto brow = [](int v,  int lr) { return v * 32 + (lr >> 5) * 64 + (lr & 31); };
  const int rA[2][2] = {{arow(0, lr0), arow(0, lr1)}, {arow(1, lr0), arow(1, lr1)}};
  const int rB[2][2] = {{brow(0, lr0), brow(0, lr1)}, {brow(1, lr0), brow(1, lr1)}};

  auto stageA = [&](int buf, int mq, int kt) {
#pragma unroll
    for (int t = 0; t < 2; ++t) {
      const int rb = rA[mq][t];
      GLOAD_LDS16(gA + (size_t)rb * K + kt * BK,
                  ldsA + buf * 16384 + rb * 64 + lane * 8);
    }
  };
  auto stageB = [&](int buf, int v, int kt) {
#pragma unroll
    for (int t = 0; t < 2; ++t) {
      const int rb = rB[v][t];
      GLOAD_LDS16(gB + (size_t)rb * K + kt * BK,
                  ldsB + buf * 16384 + rb * 64 + lane * 8);
    }
  };

  // ---- fragment reads (same proven swizzled pattern, 2-way free aliasing) --
  const int fRow = lane & 15;
  const int q4   = lane >> 4;
  const int s8   = fRow & 7;
  const int sw0  = ((q4)     ^ s8) * 8;   // kk=0 chunk
  const int sw1  = ((4 + q4) ^ s8) * 8;   // kk=1 chunk
  const int aRO  = (wr * 128 + fRow) * 64;
  const int bRO  = (wc * 64  + fRow) * 64;

  auto dsA = [&](int buf, int mq) {
    const unsigned short* p = ldsA + buf * 16384 + aRO + mq * 4096;
#pragma unroll
    for (int m = 0; m < 4; ++m) {
      a[m][0] = *(const bf16x8*)(p + m * 1024 + sw0);
      a[m][1] = *(const bf16x8*)(p + m * 1024 + sw1);
    }
  };
  auto dsB = [&](int buf, int njp, bf16x8 (&bb)[2][2]) {
    const unsigned short* p = ldsB + buf * 16384 + bRO + njp * 2048;
#pragma unroll
    for (int n = 0; n < 2; ++n) {
      bb[n][0] = *(const bf16x8*)(p + n * 1024 + sw0);
      bb[n][1] = *(const bf16x8*)(p + n * 1024 + sw1);
    }
  };

  auto mm = [&](int mq, int njp, bf16x8 (&bb)[2][2]) {
    __builtin_amdgcn_s_setprio(1);
#pragma unroll
    for (int m = 0; m < 4; ++m)
#pragma unroll
      for (int n = 0; n < 2; ++n)
#pragma unroll
        for (int k = 0; k < 2; ++k)
          acc[mq * 4 + m][njp * 2 + n] = __builtin_amdgcn_mfma_f32_16x16x32_bf16(
              a[m][k], bb[n][k], acc[mq * 4 + m][njp * 2 + n], 0, 0, 0);
    __builtin_amdgcn_s_setprio(0);
  };

  // ---- prologue: tile 0 -> buf0 (issue order matches steady-state gates) ---
  stageA(0, 0, 0); stageB(0, 0, 0); stageB(0, 1, 0); stageA(0, 1, 0);
  VM4(); BAR();

  const int niter = K / (2 * BK);   // 8 (K=1024); requires niter >= 2
  for (int i = 0; i < niter - 1; ++i) {
    const int t1 = 2 * i + 1, t2 = 2 * i + 2;
    // P0: compute buf0 (miQ0,nj01); stage buf1 A-U01
    dsA(0, 0); dsB(0, 0, b01); stageA(1, 0, t1);
    BAR(); LG0(); mm(0, 0, b01); VM4(); BAR();
    // P1: (miQ0,nj23); stage buf1 B-V0
    dsB(0, 1, b23); stageB(1, 0, t1);
    BAR(); LG0(); mm(0, 1, b23); VM4(); BAR();
    // P2: (miQ1,nj01); stage buf1 B-V1
    dsA(0, 1); stageB(1, 1, t1);
    BAR(); LG0(); mm(1, 0, b01); BAR();
    // P3: (miQ1,nj23); stage buf1 A-U23
    stageA(1, 1, t1);
    BAR(); mm(1, 1, b23); VM4(); BAR();
    // P4: compute buf1; stage buf0 A-U01 (next tile pair)
    dsA(1, 0); dsB(1, 0, b01); stageA(0, 0, t2);
    BAR(); LG0(); mm(0, 0, b01); VM4(); BAR();
    // P5
    dsB(1, 1, b23); stageB(0, 0, t2);
    BAR(); LG0(); mm(0, 1, b23); VM4(); BAR();
    // P6
    dsA(1, 1); stageB(0, 1, t2);
    BAR(); LG0(); mm(1, 0, b01); BAR();
    // P7
    stageA(0, 1, t2);
    BAR(); mm(1, 1, b23); VM4(); BAR();
  }
  // ---- peeled final iteration: no stages in P4-7; gates tighten 4->2->0 ----
  {
    const int t1 = 2 * niter - 1;
    dsA(0, 0); dsB(0, 0, b01); stageA(1, 0, t1);
    BAR(); LG0(); mm(0, 0, b01); VM4(); BAR();
    dsB(0, 1, b23); stageB(1, 0, t1);
    BAR(); LG0(); mm(0, 1, b23); VM4(); BAR();
    dsA(0, 1); stageB(1, 1, t1);
    BAR(); LG0(); mm(1, 0, b01); BAR();
    stageA(1, 1, t1);
    BAR(); mm(1, 1, b23); VM4(); BAR();
    dsA(1, 0); dsB(1, 0, b01);
    BAR(); LG0(); mm(0, 0, b01); VM2(); BAR();
    dsB(1, 1, b23);
    BAR(); LG0(); mm(0, 1, b23); VM0(); BAR();
    dsA(1, 1);
    BAR(); LG0(); mm(1, 0, b01); BAR();
    mm(1, 1, b23);
  }

  // ---- epilogue: C/D map col=lane&15, row=(lane>>4)*4+reg ----
  const int    n0 = bn * BN + wc * 64 + fRow;
  const size_t m0 = (size_t)bm * BM + wr * 128 + (q4 << 2);
#pragma unroll
  for (int nj = 0; nj < 4; ++nj) {
    const int col = n0 + nj * 16;
    const float bv = bias[col];
#pragma unroll
    for (int mi = 0; mi < 8; ++mi) {
      const size_t base = (m0 + (size_t)mi * 16) * N + col;
#pragma unroll
      for (int r = 0; r < 4; ++r)
        C[base + (size_t)r * N] = acc[mi][nj][r] + bv;
    }
  }
}

// ---------- launch ----------
extern "C" void kernel_launch(void* const* d_in, const int* in_sizes, int n_in,
                              void* d_out, int out_size, void* d_ws, size_t ws_size,
                              hipStream_t stream) {
  const float* x    = (const float*)d_in[0];
  const float* w    = (const float*)d_in[1];
  const float* bias = (const float*)d_in[2];

  const int DOUT = in_sizes[2];            // 1024
  const int DIN  = in_sizes[1] / DOUT;     // 1024
  const int M    = in_sizes[0] / DIN;      // 32768

  unsigned short* xq = (unsigned short*)d_ws;                  // M*K bf16 = 64 MB
  unsigned short* wq = xq + (size_t)M * DIN;                   // N*K bf16 =  2 MB

  hipLaunchKernelGGL(quant_x_k, dim3((size_t)M * DIN / 4 / 256), dim3(256), 0,
                     stream, x, xq);
  hipLaunchKernelGGL(quant_w_k, dim3((size_t)DOUT * DIN / 4 / 256), dim3(256), 0,
                     stream, w, wq);

  const int grid = (M / BM) * (DOUT / BN);  // 128*4 = 512
  hipLaunchKernelGGL(gemm_bt_bias, dim3(grid), dim3(512), 0, stream,
                     xq, wq, bias, (float*)d_out, M, DOUT, DIN);
}